// Round 4
// baseline (879.555 us; speedup 1.0000x reference)
//
#include <hip/hip_runtime.h>

typedef unsigned short u16;
typedef unsigned int u32;
typedef __bf16 bf16x8 __attribute__((ext_vector_type(8)));
typedef float  f32x16 __attribute__((ext_vector_type(16)));

#define NB 4
#define NN 4096
#define ND 256

__device__ __forceinline__ u16 f2bf(float x) { return __builtin_bit_cast(u16, (__bf16)x); }
__device__ __forceinline__ float bf2f(u16 x) { u32 u = (u32)x << 16; return __builtin_bit_cast(float, u); }
__device__ __forceinline__ u32 pack2(float a, float b) { return (u32)f2bf(a) | ((u32)f2bf(b) << 16); }

typedef __attribute__((address_space(1))) const u32 gas_u32;
typedef __attribute__((address_space(3))) u32 las_u32;
__device__ __forceinline__ void async_ld16(void* lds, const void* g) {
    __builtin_amdgcn_global_load_lds((gas_u32*)g, (las_u32*)lds, 16, 0, 0);
}

// ws layout (u16* base):
//  kq  : [b][strip128][s16][lane64][8]    bf16, 8 MB  (A/B-operand frags of val)
//  vp  : [b][strip128][et8*2seg][lane64][8] bf16, 8 MB (B-operand frags of (val@Wv)^T)
//  wv  : [es8][s16][lane64][8]            bf16, 128 KB
//  part: 3 x [(b*4096+q)*256+e]           bf16, 24 MB (msG=1..3 dval partials)
//  dsp : 3 x [b*4096+q]                   f32, 192 KB

// ---- pack val into fragment order ----
__global__ __launch_bounds__(256) void k_pack_val(const float* __restrict__ val, u16* __restrict__ kq) {
    __shared__ float t[32 * 257];
    int bs = blockIdx.x;
    int tid = threadIdx.x;
    const float* src = val + (size_t)bs * 32 * 256;
    #pragma unroll
    for (int k = 0; k < 8; k++) {
        int idx = tid + k * 256;
        int row = idx >> 6, c4 = idx & 63;
        float4 v = *(const float4*)(src + row * 256 + c4 * 4);
        float* p = t + row * 257 + c4 * 4;
        p[0] = v.x; p[1] = v.y; p[2] = v.z; p[3] = v.w;
    }
    __syncthreads();
    u16* dst = kq + (size_t)bs * 16 * 512;
    #pragma unroll
    for (int k = 0; k < 4; k++) {
        int flat = tid + k * 256;
        int s = flat >> 6, l = flat & 63;
        int l31 = l & 31, h = l >> 5;
        const float* p = t + l31 * 257 + s * 16 + h * 8;
        union { u16 o[8]; uint4 q; } u;
        #pragma unroll
        for (int j = 0; j < 8; j++) u.o[j] = f2bf(p[j]);
        *(uint4*)(dst + (size_t)flat * 8) = u.q;
    }
}

// ---- pack Wv^T frags ----
__global__ __launch_bounds__(256) void k_pack_wv(const float* __restrict__ Wv, u16* __restrict__ wv) {
    int tid = threadIdx.x;
    __shared__ u16 t2[256 * 33];
    int es = blockIdx.x, e0 = es * 32;
    #pragma unroll
    for (int k = 0; k < 8; k++) {
        int idx = tid + k * 256;
        int row = idx >> 3, c4 = idx & 7;
        float4 v = *(const float4*)(Wv + row * 256 + e0 + c4 * 4);
        u16* p = t2 + row * 33 + c4 * 4;
        p[0] = f2bf(v.x); p[1] = f2bf(v.y); p[2] = f2bf(v.z); p[3] = f2bf(v.w);
    }
    __syncthreads();
    u16* dst = wv + (size_t)es * 16 * 512;
    #pragma unroll
    for (int k = 0; k < 4; k++) {
        int flat = tid + k * 256;
        int s = flat >> 6, l = flat & 63;
        int l31 = l & 31, h = l >> 5;
        union { u16 o[8]; uint4 q; } u;
        #pragma unroll
        for (int j = 0; j < 8; j++) u.o[j] = t2[(s * 16 + h * 8 + j) * 33 + l31];
        *(uint4*)(dst + (size_t)flat * 8) = u.q;
    }
}

// ---- pv^T = Wv^T x val^T in B-operand fragment order ----
__global__ __launch_bounds__(64) void k_pv(const u16* __restrict__ kq, const u16* __restrict__ wv,
                                           u16* __restrict__ vp) {
    __shared__ u16 tp[32 * 40];
    int wid = blockIdx.x;
    int lane = threadIdx.x;
    int l31 = lane & 31, h = lane >> 5;
    int bb = wid >> 8, es = (wid >> 5) & 7, qb = wid & 31;
    const u16* wvb = wv + (size_t)(es * 16) * 512 + lane * 8;
    const u16* kqb = kq + ((size_t)(bb * 128 + qb * 4) * 16) * 512 + lane * 8;
    f32x16 acc[4] = {};
    for (int s = 0; s < 16; s++) {
        bf16x8 af = *(const bf16x8*)(wvb + s * 512);
        #pragma unroll
        for (int qt = 0; qt < 4; qt++) {
            bf16x8 bfr = *(const bf16x8*)(kqb + (size_t)(qt * 16 + s) * 512);
            acc[qt] = __builtin_amdgcn_mfma_f32_32x32x16_bf16(af, bfr, acc[qt], 0, 0, 0);
        }
    }
    #pragma unroll
    for (int qt = 0; qt < 4; qt++) {
        #pragma unroll
        for (int r = 0; r < 16; r++) {
            int erow = (r & 3) + 8 * (r >> 2) + 4 * h;
            tp[erow * 40 + l31] = f2bf(acc[qt][r]);
        }
        __syncthreads();
        #pragma unroll
        for (int seg = 0; seg < 2; seg++) {
            uint4 v = *(const uint4*)(tp + l31 * 40 + seg * 16 + h * 8);
            *(uint4*)(vp + (((size_t)(bb * 128 + qb * 4 + qt) * 16) + es * 2 + seg) * 512 + lane * 8) = v;
        }
        __syncthreads();
    }
}

// ---- main: q=64/wave register blocking, LDS dbuf, 1 barrier/m-tile ----
__global__ __launch_bounds__(512, 2) void k_main(const u16* __restrict__ kq,
                                                 const u16* __restrict__ vp,
                                                 const float* __restrict__ state,
                                                 u16* __restrict__ part, float* __restrict__ dsp,
                                                 float* __restrict__ ds_out, float* __restrict__ dval_out) {
    __shared__ u16 stage[2 * 32768];           // 128 KB dbuf: per buf [K(2 strips)|V(2 strips)]
    __shared__ float dsq[256];

    int tid = threadIdx.x;
    int w = tid >> 6, lane = tid & 63;
    int l31 = lane & 31, h = lane >> 5;
    int s4 = w & 3, msL = w >> 2;

    int id = blockIdx.x;
    int xcd = id & 7;
    int bb = xcd >> 1;
    int t6 = ((xcd & 1) << 5) | (id >> 3);     // [0,64)
    int qb = t6 >> 2, msG = t6 & 3;            // 16 q-tiles x 4 m-splits
    int q0 = qb * 256;
    int m_base = msG * 1024;

    // Q fragments resident: 2 q-sets of 32 (wave covers q = q0 + s4*64 .. +63)
    bf16x8 qf[2][16];
    #pragma unroll
    for (int qs = 0; qs < 2; qs++) {
        const u16* qsrc = kq + ((size_t)(bb * 128 + qb * 8 + s4 * 2 + qs) * 16) * 512 + lane * 8;
        #pragma unroll
        for (int s = 0; s < 16; s++) qf[qs][s] = *(const bf16x8*)(qsrc + (size_t)s * 512);
    }

    f32x16 oacc[2][8] = {};
    float dsacc[2] = {0.0f, 0.0f};

    // stage tile 0
    {
        int mstrip0 = m_base >> 5;
        const u16* srcK = kq + ((size_t)(bb * 128 + mstrip0) * 16) * 512;
        const u16* srcV = vp + ((size_t)(bb * 128 + mstrip0) * 16) * 512;
        #pragma unroll
        for (int k = 0; k < 8; k++) {
            int cb = w * 64 + k * 512;
            int c = cb + lane;
            const u16* s = (cb < 2048 ? srcK : srcV) + (size_t)(c & 2047) * 8;
            async_ld16(stage + (size_t)cb * 8, s);
        }
    }
    __syncthreads();

    for (int mt = 0; mt < 16; mt++) {
        int buf = mt & 1;
        u16* stageb = stage + buf * 32768;
        if (mt + 1 < 16) {
            int mstrip0 = (m_base >> 5) + (mt + 1) * 2;
            const u16* srcK = kq + ((size_t)(bb * 128 + mstrip0) * 16) * 512;
            const u16* srcV = vp + ((size_t)(bb * 128 + mstrip0) * 16) * 512;
            u16* dstb = stage + (buf ^ 1) * 32768;
            #pragma unroll
            for (int k = 0; k < 8; k++) {
                int cb = w * 64 + k * 512;
                int c = cb + lane;
                const u16* s = (cb < 2048 ? srcK : srcV) + (size_t)(c & 2047) * 8;
                async_ld16(dstb + (size_t)cb * 8, s);
            }
        }

        // state broadcast loads for this wave's m-half (rows g*8+4h+0..3)
        const float* stp = state + bb * 4096 + m_base + mt * 64 + msL * 32;
        float4 stv[4];
        #pragma unroll
        for (int g = 0; g < 4; g++) stv[g] = *(const float4*)(stp + g * 8 + h * 4);

        // S^T = K x Q^T for both q-sets; each K-frag read feeds 2 MFMAs
        const u16* kbuf = stageb + msL * 8192;
        f32x16 sacc0 = {}, sacc1 = {};
        #pragma unroll
        for (int s = 0; s < 16; s++) {
            bf16x8 kf = *(const bf16x8*)(kbuf + (s * 64 + lane) * 8);
            sacc0 = __builtin_amdgcn_mfma_f32_32x32x16_bf16(kf, qf[0][s], sacc0, 0, 0, 0);
            sacc1 = __builtin_amdgcn_mfma_f32_32x32x16_bf16(kf, qf[1][s], sacc1, 0, 0, 0);
        }

        // softsign + ds partial + C->A exchange, per q-set
        bf16x8 pf[2][2];
        #pragma unroll
        for (int qs = 0; qs < 2; qs++) {
            f32x16 sacc = qs ? sacc1 : sacc0;
            float ds = dsacc[qs];
            u32 c[8];
            #pragma unroll
            for (int i = 0; i < 8; i++) {
                float a = sacc[2 * i], b = sacc[2 * i + 1];
                float pa = a * __builtin_amdgcn_rcpf(1.0f + fabsf(a));
                float pb = b * __builtin_amdgcn_rcpf(1.0f + fabsf(b));
                ds += pa * ((const float*)&stv[(2 * i) >> 2])[(2 * i) & 3];
                ds += pb * ((const float*)&stv[(2 * i + 1) >> 2])[(2 * i + 1) & 3];
                c[i] = pack2(pa, pb);
            }
            dsacc[qs] = ds;
            u32 s0a = h ? c[0] : c[2], s0b = h ? c[1] : c[3];
            u32 s1a = h ? c[4] : c[6], s1b = h ? c[5] : c[7];
            u32 r0a = (u32)__shfl_xor((int)s0a, 32);
            u32 r0b = (u32)__shfl_xor((int)s0b, 32);
            u32 r1a = (u32)__shfl_xor((int)s1a, 32);
            u32 r1b = (u32)__shfl_xor((int)s1b, 32);
            union { u32 wd[4]; bf16x8 v; } p0u, p1u;
            if (h == 0) {
                p0u.wd[0] = c[0]; p0u.wd[1] = c[1]; p0u.wd[2] = r0a; p0u.wd[3] = r0b;
                p1u.wd[0] = c[4]; p1u.wd[1] = c[5]; p1u.wd[2] = r1a; p1u.wd[3] = r1b;
            } else {
                p0u.wd[0] = r0a; p0u.wd[1] = r0b; p0u.wd[2] = c[2]; p0u.wd[3] = c[3];
                p1u.wd[0] = r1a; p1u.wd[1] = r1b; p1u.wd[2] = c[6]; p1u.wd[3] = c[7];
            }
            pf[qs][0] = p0u.v; pf[qs][1] = p1u.v;
        }

        // O += P x Vt; each V-frag read feeds 2 MFMAs
        const u16* vbuf = stageb + 16384 + msL * 8192;
        #pragma unroll
        for (int et = 0; et < 8; et++) {
            bf16x8 v0 = *(const bf16x8*)(vbuf + ((et * 2 + 0) * 64 + lane) * 8);
            bf16x8 v1 = *(const bf16x8*)(vbuf + ((et * 2 + 1) * 64 + lane) * 8);
            oacc[0][et] = __builtin_amdgcn_mfma_f32_32x32x16_bf16(pf[0][0], v0, oacc[0][et], 0, 0, 0);
            oacc[0][et] = __builtin_amdgcn_mfma_f32_32x32x16_bf16(pf[0][1], v1, oacc[0][et], 0, 0, 0);
            oacc[1][et] = __builtin_amdgcn_mfma_f32_32x32x16_bf16(pf[1][0], v0, oacc[1][et], 0, 0, 0);
            oacc[1][et] = __builtin_amdgcn_mfma_f32_32x32x16_bf16(pf[1][1], v1, oacc[1][et], 0, 0, 0);
        }
        __syncthreads();   // single barrier per tile (drains async stage)
    }

    // ---- epilogue ----
    float* redf = (float*)stage;               // 128 KB = one q-set chunk (128 rows x 256 e)
    dsacc[0] += __shfl_xor(dsacc[0], 32);
    dsacc[1] += __shfl_xor(dsacc[1], 32);

    #pragma unroll
    for (int qs = 0; qs < 2; qs++) {
        if (msL == 1) {
            #pragma unroll
            for (int et = 0; et < 8; et++)
                #pragma unroll
                for (int r = 0; r < 16; r++) {
                    int row = (r & 3) + 8 * (r >> 2) + 4 * h;
                    redf[(s4 * 32 + row) * 256 + et * 32 + l31] = oacc[qs][et][r];
                }
            if (qs == 0 && lane < 32) {
                dsq[s4 * 64 + lane] = dsacc[0];
                dsq[s4 * 64 + 32 + lane] = dsacc[1];
            }
        }
        __syncthreads();
        if (msL == 0) {
            #pragma unroll
            for (int et = 0; et < 8; et++)
                #pragma unroll
                for (int r = 0; r < 16; r++) {
                    int row = (r & 3) + 8 * (r >> 2) + 4 * h;
                    float v = oacc[qs][et][r] + redf[(s4 * 32 + row) * 256 + et * 32 + l31];
                    size_t oidx = ((size_t)(bb * 4096 + q0 + s4 * 64 + qs * 32 + row)) * 256 + et * 32 + l31;
                    if (msG == 0) dval_out[oidx] = v;
                    else part[(size_t)(msG - 1) * (NB * NN * ND) + oidx] = f2bf(v);
                }
            if (qs == 0 && lane < 32) {
                float d0 = dsacc[0] + dsq[s4 * 64 + lane];
                float d1 = dsacc[1] + dsq[s4 * 64 + 32 + lane];
                int qi = bb * 4096 + q0 + s4 * 64 + lane;
                if (msG == 0) { ds_out[qi] = d0; ds_out[qi + 32] = d1; }
                else { dsp[(msG - 1) * (NB * NN) + qi] = d0; dsp[(msG - 1) * (NB * NN) + qi + 32] = d1; }
            }
        }
        __syncthreads();
    }
}

// ---- combine the 3 m-split partials ----
__global__ __launch_bounds__(256) void k_combine(const u16* __restrict__ part, const float* __restrict__ dsp,
                                                 float* __restrict__ ds_out, float* __restrict__ dval_out) {
    int b = blockIdx.x;
    if (b < 4096) {
        int i = b * 256 + threadIdx.x;
        float4 d = ((const float4*)dval_out)[i];
        #pragma unroll
        for (int j = 0; j < 3; j++) {
            ushort4 p = ((const ushort4*)(part + (size_t)j * (NB * NN * ND)))[i];
            d.x += bf2f(p.x); d.y += bf2f(p.y); d.z += bf2f(p.z); d.w += bf2f(p.w);
        }
        ((float4*)dval_out)[i] = d;
    } else {
        int k = (b - 4096) * 256 + threadIdx.x;
        ds_out[k] += dsp[k] + dsp[NB * NN + k] + dsp[2 * NB * NN + k];
    }
}

extern "C" void kernel_launch(void* const* d_in, const int* in_sizes, int n_in,
                              void* d_out, int out_size, void* d_ws, size_t ws_size,
                              hipStream_t stream) {
    const float* val   = (const float*)d_in[0];
    const float* state = (const float*)d_in[1];
    const float* Wv    = (const float*)d_in[2];

    float* ds_out   = (float*)d_out;
    float* dval_out = ds_out + NB * NN;

    u16* kq   = (u16*)d_ws;                                 // 8 MB
    u16* vp   = kq + (size_t)NB * NN * ND;                  // 8 MB
    u16* wv   = vp + (size_t)NB * NN * ND;                  // 128 KB
    u16* part = wv + 8 * 16 * 512;                          // 24 MB (3 sets)
    float* dsp = (float*)(part + (size_t)3 * NB * NN * ND); // 192 KB (3 sets)

    k_pack_val<<<NB * NN / 32, 256, 0, stream>>>(val, kq);
    k_pack_wv<<<8, 256, 0, stream>>>(Wv, wv);
    k_pv<<<1024, 64, 0, stream>>>(kq, wv, vp);
    k_main<<<256, 512, 0, stream>>>(kq, vp, state, part, dsp, ds_out, dval_out);
    k_combine<<<4096 + 64, 256, 0, stream>>>(part, dsp, ds_out, dval_out);
}

// Round 5
// 160.449 us; speedup vs baseline: 5.4819x; 5.4819x over previous
//
#include <hip/hip_runtime.h>

typedef unsigned short u16;
typedef unsigned char u8;
typedef unsigned int u32;
typedef __bf16 bf16x8 __attribute__((ext_vector_type(8)));
typedef float  f32x16 __attribute__((ext_vector_type(16)));
typedef int    i32x4  __attribute__((ext_vector_type(4)));
typedef int    i32x16 __attribute__((ext_vector_type(16)));

#define NB 4
#define NN 4096
#define ND 256

#define SVAL_INV (127.0f / 6.0f)      // val, pv quant scale
#define S2       (36.0f / 16129.0f)   // score dequant = (6/127)^2
#define OD       (6.0f / 16129.0f)    // O dequant = (1/127)*(6/127)

__device__ __forceinline__ u16 f2bf(float x) { return __builtin_bit_cast(u16, (__bf16)x); }

typedef __attribute__((address_space(1))) const u32 gas_u32;
typedef __attribute__((address_space(3))) u32 las_u32;
__device__ __forceinline__ void async_ld16(void* lds, const void* g) {
    __builtin_amdgcn_global_load_lds((gas_u32*)g, (las_u32*)lds, 16, 0, 0);
}

__device__ __forceinline__ int q8(float x) {
    x = fminf(fmaxf(x, -127.0f), 127.0f);
    return (int)rintf(x);
}
__device__ __forceinline__ u32 pack4(int a, int b, int c, int d) {
    return (u32)(a & 255) | ((u32)(b & 255) << 8) | ((u32)(c & 255) << 16) | ((u32)d << 24);
}

// ws layout:
//  kq8 : [b*128+strip32][s8][lane64][16B]  i8 val frags (A/B operand), 4 MB
//  vp8 : [b*128+strip32][et8][lane64][16B] i8 pv^T frags (B operand), 4 MB
//  kq  : [b*128+strip32][s16][lane64][8]   bf16 val frags (for k_pv), 8 MB
//  wv  : [es8][s16][lane64][8]             bf16 Wv^T frags, 128 KB

// ---- pack val: bf16 frags (for k_pv) + i8 frags (for k_main) ----
__global__ __launch_bounds__(256) void k_pack_val(const float* __restrict__ val,
                                                  u16* __restrict__ kq, u8* __restrict__ kq8) {
    __shared__ float t[32 * 257];
    int bs = blockIdx.x;                       // global 32-row strip
    int tid = threadIdx.x;
    const float* src = val + (size_t)bs * 32 * 256;
    #pragma unroll
    for (int k = 0; k < 8; k++) {
        int idx = tid + k * 256;
        int row = idx >> 6, c4 = idx & 63;
        float4 v = *(const float4*)(src + row * 256 + c4 * 4);
        float* p = t + row * 257 + c4 * 4;
        p[0] = v.x; p[1] = v.y; p[2] = v.z; p[3] = v.w;
    }
    __syncthreads();
    // bf16 frags
    u16* dst = kq + (size_t)bs * 16 * 512;
    #pragma unroll
    for (int k = 0; k < 4; k++) {
        int flat = tid + k * 256;
        int s = flat >> 6, l = flat & 63;
        int l31 = l & 31, h = l >> 5;
        const float* p = t + l31 * 257 + s * 16 + h * 8;
        union { u16 o[8]; uint4 q; } u;
        #pragma unroll
        for (int j = 0; j < 8; j++) u.o[j] = f2bf(p[j]);
        *(uint4*)(dst + (size_t)flat * 8) = u.q;
    }
    // i8 frags: frag s covers d = s*32 + h*16 + j
    u8* dst8 = kq8 + (size_t)bs * 8 * 1024;
    #pragma unroll
    for (int k = 0; k < 2; k++) {
        int flat = tid + k * 256;              // [0,512): s*64 + l
        int s = flat >> 6, l = flat & 63;
        int l31 = l & 31, h = l >> 5;
        const float* p = t + l31 * 257 + s * 32 + h * 16;
        union { u8 b[16]; i32x4 v; } u;
        #pragma unroll
        for (int j = 0; j < 16; j++) u.b[j] = (u8)(q8(p[j] * SVAL_INV) & 255);
        *(i32x4*)(dst8 + (size_t)flat * 16) = u.v;
    }
}

// ---- pack Wv^T bf16 frags ----
__global__ __launch_bounds__(256) void k_pack_wv(const float* __restrict__ Wv, u16* __restrict__ wv) {
    int tid = threadIdx.x;
    __shared__ u16 t2[256 * 33];
    int es = blockIdx.x, e0 = es * 32;
    #pragma unroll
    for (int k = 0; k < 8; k++) {
        int idx = tid + k * 256;
        int row = idx >> 3, c4 = idx & 7;
        float4 v = *(const float4*)(Wv + row * 256 + e0 + c4 * 4);
        u16* p = t2 + row * 33 + c4 * 4;
        p[0] = f2bf(v.x); p[1] = f2bf(v.y); p[2] = f2bf(v.z); p[3] = f2bf(v.w);
    }
    __syncthreads();
    u16* dst = wv + (size_t)es * 16 * 512;
    #pragma unroll
    for (int k = 0; k < 4; k++) {
        int flat = tid + k * 256;
        int s = flat >> 6, l = flat & 63;
        int l31 = l & 31, h = l >> 5;
        union { u16 o[8]; uint4 q; } u;
        #pragma unroll
        for (int j = 0; j < 8; j++) u.o[j] = t2[(s * 16 + h * 8 + j) * 33 + l31];
        *(uint4*)(dst + (size_t)flat * 8) = u.q;
    }
}

// ---- pv^T = Wv^T x val^T (bf16 MFMA), emitted as i8 B-operand frags ----
__global__ __launch_bounds__(64) void k_pv(const u16* __restrict__ kq, const u16* __restrict__ wv,
                                           u8* __restrict__ vp8) {
    __shared__ u8 tp[32 * 48];                 // [e-local][m-local], row stride 48
    int wid = blockIdx.x;                      // 1024
    int lane = threadIdx.x;
    int l31 = lane & 31, h = lane >> 5;
    int bb = wid >> 8, es = (wid >> 5) & 7, qb = wid & 31;   // qb indexes m in k_main terms
    const u16* wvb = wv + (size_t)(es * 16) * 512 + lane * 8;
    const u16* kqb = kq + ((size_t)(bb * 128 + qb * 4) * 16) * 512 + lane * 8;
    f32x16 acc[4] = {};
    for (int s = 0; s < 16; s++) {
        bf16x8 af = *(const bf16x8*)(wvb + s * 512);
        #pragma unroll
        for (int qt = 0; qt < 4; qt++) {
            bf16x8 bfr = *(const bf16x8*)(kqb + (size_t)(qt * 16 + s) * 512);
            acc[qt] = __builtin_amdgcn_mfma_f32_32x32x16_bf16(af, bfr, acc[qt], 0, 0, 0);
        }
    }
    #pragma unroll
    for (int qt = 0; qt < 4; qt++) {
        #pragma unroll
        for (int r = 0; r < 16; r++) {
            int erow = (r & 3) + 8 * (r >> 2) + 4 * h;
            tp[erow * 48 + l31] = (u8)(q8(acc[qt][r] * SVAL_INV) & 255);
        }
        __syncthreads();
        i32x4 v = *(const i32x4*)(tp + l31 * 48 + h * 16);
        *(i32x4*)(vp8 + ((size_t)((bb * 128 + qb * 4 + qt) * 8 + es)) * 1024 + lane * 16) = v;
        __syncthreads();
    }
}

// ---- main: i8 flash softsign; 2 q-strips x 4 m-quarters; m-tile 128; no m-split ----
__global__ __launch_bounds__(512, 2) void k_main(const u8* __restrict__ kq8,
                                                 const u8* __restrict__ vp8,
                                                 const float* __restrict__ state,
                                                 float* __restrict__ ds_out,
                                                 float* __restrict__ dval_out) {
    __shared__ u8 stage[2 * 65536];            // 128 KB dbuf: per buf [K 32KB | V 32KB]
    __shared__ float dsq[2][4][32];

    int tid = threadIdx.x;
    int w = tid >> 6, lane = tid & 63;
    int l31 = lane & 31, h = lane >> 5;
    int strip = w & 1, mq = w >> 1;            // q-strip (2x32), m-quarter (4x32)

    int id = blockIdx.x;
    int xcd = id & 7;
    int bb = xcd >> 1;
    int qt6 = ((xcd & 1) << 5) | (id >> 3);    // [0,64)
    int q0 = qt6 * 64;

    // Q fragments resident (B-operand, i8): 8 frags x 4 regs = 32 VGPR
    i32x4 qf[8];
    {
        const u8* qsrc = kq8 + ((size_t)((bb * 128 + qt6 * 2 + strip) * 8)) * 1024 + lane * 16;
        #pragma unroll
        for (int s = 0; s < 8; s++) qf[s] = *(const i32x4*)(qsrc + (size_t)s * 1024);
    }

    i32x16 oacc[8] = {};
    float ds = 0.0f;

    // stage tile 0
    {
        const u8* srcK = kq8 + (size_t)(bb * 128) * 8192;
        const u8* srcV = vp8 + (size_t)(bb * 128) * 8192;
        #pragma unroll
        for (int k = 0; k < 8; k++) {
            int c = w + k * 8;                 // chunk [0,64)
            const u8* s = (c < 32) ? (srcK + (size_t)c * 1024 + lane * 16)
                                   : (srcV + (size_t)(c - 32) * 1024 + lane * 16);
            async_ld16(stage + (size_t)c * 1024, s);
        }
    }
    __syncthreads();

    for (int mt = 0; mt < 32; mt++) {
        u8* buf = stage + (mt & 1) * 65536;
        if (mt + 1 < 32) {
            const u8* srcK = kq8 + (size_t)(bb * 128 + (mt + 1) * 4) * 8192;
            const u8* srcV = vp8 + (size_t)(bb * 128 + (mt + 1) * 4) * 8192;
            u8* dstb = stage + ((mt + 1) & 1) * 65536;
            #pragma unroll
            for (int k = 0; k < 8; k++) {
                int c = w + k * 8;
                const u8* s = (c < 32) ? (srcK + (size_t)c * 1024 + lane * 16)
                                       : (srcV + (size_t)(c - 32) * 1024 + lane * 16);
                async_ld16(dstb + (size_t)c * 1024, s);
            }
        }

        // S^T = K x Q^T : D[m-local][q], 8 MFMAs (K=32 each)
        const u8* kbuf = buf + mq * 8192;
        i32x16 sacc = {};
        #pragma unroll
        for (int s = 0; s < 8; s++) {
            i32x4 kf = *(const i32x4*)(kbuf + s * 1024 + lane * 16);
            sacc = __builtin_amdgcn_mfma_i32_32x32x32_i8(kf, qf[s], sacc, 0, 0, 0);
        }

        // state (uniform per h,r): rows m = (r&3)+8*(r>>2)+4h
        const float* stb = state + bb * 4096 + mt * 128 + mq * 32;
        float4 stv[4];
        #pragma unroll
        for (int g = 0; g < 4; g++) stv[g] = *(const float4*)(stb + g * 8 + h * 4);

        // dequant -> softsign -> ds(FP32, protected) -> i8 quantize P
        int ai[16];
        #pragma unroll
        for (int r = 0; r < 16; r++) {
            float x = (float)sacc[r] * S2;
            float p = x * __builtin_amdgcn_rcpf(1.0f + fabsf(x));
            ds += p * ((const float*)&stv[r >> 2])[r & 3];
            ai[r] = (int)rintf(p * 127.0f);
        }
        u32 w0 = pack4(ai[0], ai[1], ai[2], ai[3]);
        u32 w1 = pack4(ai[4], ai[5], ai[6], ai[7]);
        u32 w2 = pack4(ai[8], ai[9], ai[10], ai[11]);
        u32 w3 = pack4(ai[12], ai[13], ai[14], ai[15]);
        u32 x0 = (u32)__shfl_xor((int)w0, 32);
        u32 x1 = (u32)__shfl_xor((int)w1, 32);
        u32 x2 = (u32)__shfl_xor((int)w2, 32);
        u32 x3 = (u32)__shfl_xor((int)w3, 32);
        union { u32 wd[4]; i32x4 v; } pu;
        if (h == 0) { pu.wd[0] = w0; pu.wd[1] = x0; pu.wd[2] = w1; pu.wd[3] = x1; }
        else        { pu.wd[0] = x2; pu.wd[1] = w2; pu.wd[2] = x3; pu.wd[3] = w3; }
        i32x4 pf = pu.v;

        // O += P x Vt : 8 MFMAs (K=32 covers the full m-quarter)
        const u8* vbuf = buf + 32768 + mq * 8192;
        #pragma unroll
        for (int et = 0; et < 8; et++) {
            i32x4 vf = *(const i32x4*)(vbuf + et * 1024 + lane * 16);
            oacc[et] = __builtin_amdgcn_mfma_i32_32x32x32_i8(pf, vf, oacc[et], 0, 0, 0);
        }
        __syncthreads();   // one barrier per tile: drains async stage, protects buffers
    }

    // ---- epilogue: 4-way m-quarter reduction (i32 exact), then dequant ----
    ds += __shfl_xor(ds, 32);
    if (lane < 32) dsq[strip][mq][lane] = ds;

    int* redi = (int*)stage;                   // 4 regions x 32 KB (8192 dwords)
    if (mq >= 2) {
        int reg = strip * 2 + (mq - 2);
        #pragma unroll
        for (int et = 0; et < 8; et++)
            #pragma unroll
            for (int r = 0; r < 16; r++) {
                int row = (r & 3) + 8 * (r >> 2) + 4 * h;
                redi[reg * 8192 + row * 256 + et * 32 + l31] = oacc[et][r];
            }
    }
    __syncthreads();
    if (mq < 2) {
        int reg = strip * 2 + mq;
        #pragma unroll
        for (int et = 0; et < 8; et++)
            #pragma unroll
            for (int r = 0; r < 16; r++) {
                int row = (r & 3) + 8 * (r >> 2) + 4 * h;
                oacc[et][r] += redi[reg * 8192 + row * 256 + et * 32 + l31];
            }
    }
    __syncthreads();
    if (mq == 1) {
        #pragma unroll
        for (int et = 0; et < 8; et++)
            #pragma unroll
            for (int r = 0; r < 16; r++) {
                int row = (r & 3) + 8 * (r >> 2) + 4 * h;
                redi[strip * 8192 + row * 256 + et * 32 + l31] = oacc[et][r];
            }
    }
    __syncthreads();
    if (mq == 0) {
        #pragma unroll
        for (int et = 0; et < 8; et++)
            #pragma unroll
            for (int r = 0; r < 16; r++) {
                int row = (r & 3) + 8 * (r >> 2) + 4 * h;
                int sum = oacc[et][r] + redi[strip * 8192 + row * 256 + et * 32 + l31];
                dval_out[((size_t)(bb * 4096 + q0 + strip * 32 + row)) * 256 + et * 32 + l31] =
                    (float)sum * OD;
            }
        if (lane < 32) {
            float d = dsq[strip][0][lane] + dsq[strip][1][lane] + dsq[strip][2][lane] + dsq[strip][3][lane];
            ds_out[bb * 4096 + q0 + strip * 32 + lane] = d;
        }
    }
}

extern "C" void kernel_launch(void* const* d_in, const int* in_sizes, int n_in,
                              void* d_out, int out_size, void* d_ws, size_t ws_size,
                              hipStream_t stream) {
    const float* val   = (const float*)d_in[0];
    const float* state = (const float*)d_in[1];
    const float* Wv    = (const float*)d_in[2];

    float* ds_out   = (float*)d_out;
    float* dval_out = ds_out + NB * NN;

    u8*  kq8 = (u8*)d_ws;                                   // 4 MB
    u8*  vp8 = kq8 + (size_t)NB * NN * ND;                  // 4 MB
    u16* kq  = (u16*)(vp8 + (size_t)NB * NN * ND);          // 8 MB
    u16* wv  = kq + (size_t)NB * NN * ND;                   // 128 KB

    k_pack_val<<<NB * NN / 32, 256, 0, stream>>>(val, kq, kq8);
    k_pack_wv<<<8, 256, 0, stream>>>(Wv, wv);
    k_pv<<<1024, 64, 0, stream>>>(kq, wv, vp8);
    k_main<<<256, 512, 0, stream>>>(kq8, vp8, state, ds_out, dval_out);
}